// Round 5
// baseline (597.144 us; speedup 1.0000x reference)
//
#include <hip/hip_runtime.h>
#include <math.h>

typedef unsigned short u16;
typedef unsigned int u32;
typedef short short8 __attribute__((ext_vector_type(8)));
typedef __bf16 bf16x8 __attribute__((ext_vector_type(8)));
typedef float f32x4 __attribute__((ext_vector_type(4)));
typedef u32 u32x4 __attribute__((ext_vector_type(4)));

typedef const __attribute__((address_space(1))) void* as1cv;
typedef __attribute__((address_space(3))) void* as3v;

__device__ __forceinline__ void gload16(const void* g, void* l) {
    // async global->LDS DMA, 16B/lane; LDS dest = uniform base + lane*16
    __builtin_amdgcn_global_load_lds((as1cv)g, (as3v)l, 16, 0, 0);
}

__device__ __forceinline__ float b2f(u16 u) {
    union { u32 i; float f; } v; v.i = ((u32)u) << 16; return v.f;
}
__device__ __forceinline__ float b2f_lo(u32 q) {
    union { u32 i; float f; } v; v.i = q << 16; return v.f;
}
__device__ __forceinline__ float b2f_hi(u32 q) {
    union { u32 i; float f; } v; v.i = q & 0xffff0000u; return v.f;
}
__device__ __forceinline__ u16 f2b(float f) {
    union { float f; u32 i; } v; v.f = f;
    u32 i = v.i;
    u32 r = (i + 0x7fffu + ((i >> 16) & 1u)) >> 16;   // RNE fp32 -> bf16
    return (u16)r;
}
__device__ __forceinline__ u32 pack2(u16 a, u16 b) { return (u32)a | ((u32)b << 16); }

// ---------- device helpers (all phases live in the ONE named kernel) ----------

// segment softmax + aggregate. Persistent waves (grid 4096 blocks = 16K waves);
// lane l owns channels 8l..8l+7 (head = l>>4). No max-subtraction (|e| small).
// v2: 8-edge groups, wave-uniform indices forced to SGPR via readfirstlane
// (scalar col/rowptr loads, SGPR gather bases -> no per-edge VALU addr math),
// tail clamped to end-1 with p masked to 0 (keeps 8 gathers in flight).
__device__ void agg_dev(const int* __restrict__ rowptr, const int* __restrict__ col,
                        const float* __restrict__ asrc, const float* __restrict__ adst,
                        const u16* __restrict__ hb, const float* __restrict__ bias,
                        u16* __restrict__ outb, int elu, int NODES) {
    const int wid = __builtin_amdgcn_readfirstlane((blockIdx.x * 256 + threadIdx.x) >> 6);
    const int nwaves = gridDim.x << 2;
    const int l = threadIdx.x & 63;
    const int hd = l >> 4;
    const int cbase = 8 * l;
    float bv[8];
#pragma unroll
    for (int c = 0; c < 8; c++) bv[c] = bias[cbase + c];

    for (int n = wid; n < NODES; n += nwaves) {
        const int beg = __builtin_amdgcn_readfirstlane(rowptr[n]);
        const int end = __builtin_amdgcn_readfirstlane(rowptr[n + 1]);
        const float ad = adst[n * 4 + hd];
        float acc0[8], acc1[8];
#pragma unroll
        for (int c = 0; c < 8; c++) { acc0[c] = 0.f; acc1[c] = 0.f; }
        float ss0 = 0.f, ss1 = 0.f;
        for (int j = beg; j < end; j += 8) {
            int s[8];
#pragma unroll
            for (int q = 0; q < 8; q++) {
                int jq = j + q;
                jq = jq < end ? jq : end - 1;          // scalar clamp (self-loops => end>beg)
                s[q] = __builtin_amdgcn_readfirstlane(col[jq]);
            }
            u32x4 g[8];
#pragma unroll
            for (int q = 0; q < 8; q++)
                g[q] = *(const u32x4*)(hb + (size_t)s[q] * 512 + cbase);
            float p[8];
#pragma unroll
            for (int q = 0; q < 8; q++) {
                float e = asrc[(size_t)s[q] * 4 + hd] + ad;
                e = e > 0.f ? e : 0.2f * e;
                float pe = __expf(e);
                p[q] = (j + q < end) ? pe : 0.f;       // mask tail after exp (no NaN path)
            }
#pragma unroll
            for (int q = 0; q < 8; q += 2) {
                ss0 += p[q]; ss1 += p[q + 1];
#pragma unroll
                for (int u = 0; u < 4; u++) {
                    acc0[2 * u]     += p[q]     * b2f_lo(g[q][u]);
                    acc0[2 * u + 1] += p[q]     * b2f_hi(g[q][u]);
                    acc1[2 * u]     += p[q + 1] * b2f_lo(g[q + 1][u]);
                    acc1[2 * u + 1] += p[q + 1] * b2f_hi(g[q + 1][u]);
                }
            }
        }
        float inv = 1.f / (ss0 + ss1 + 1e-16f);
        float v[8];
#pragma unroll
        for (int c = 0; c < 8; c++) {
            float tv = (acc0[c] + acc1[c]) * inv + bv[c];
            if (elu) tv = tv > 0.f ? tv : expm1f(tv);
            v[c] = tv;
        }
        u32x4 ov;
        ov[0] = pack2(f2b(v[0]), f2b(v[1]));
        ov[1] = pack2(f2b(v[2]), f2b(v[3]));
        ov[2] = pack2(f2b(v[4]), f2b(v[5]));
        ov[3] = pack2(f2b(v[6]), f2b(v[7]));
        *(u32x4*)(outb + (size_t)n * 512 + cbase) = ov;
    }
}

// MFMA GEMM: acc = A bf16[M,K] @ Bt bf16[N,K]^T, fp32 accum.
// 128x128 tile, 4 waves 2x2, K multiple of 32 (>=96).
// v6: TWO m-tiles per block (consecutive, same n0) — amortizes per-block
//     prologue (3-tile HBM fill) + epilogue (C-write / shfl-reduce) over 2x
//     work; B-panel L2-warm for tile 2; ~1 residency round (784 blocks).
//     K-loop keeps v5's 3-buffer counted-vmcnt pipeline. Source-swizzled
//     staging (conflict-free ds_read_b128); bijective XCD-chunk remap.
// act 0: store C bf16.  act 1: relu(+bias), store C bf16.
// act 2: relu(+bias), NO C store; fused logits: out[row,k] = z-row . Wc2 + bc2.
// aS != nullptr (with act 0): fused alpha epilogue (stores C too).
__device__ void gemm_dev(const u16* __restrict__ A, const u16* __restrict__ Bt,
                         u16* __restrict__ C, const float* __restrict__ bias,
                         const float* __restrict__ aS, const float* __restrict__ aD,
                         float* __restrict__ asr, float* __restrict__ ads,
                         const float* __restrict__ Wc2, const float* __restrict__ bc2,
                         float* __restrict__ outp,
                         int M, int N, int K, int act, char* shm) {
    const int t = threadIdx.x;
    const int l = t & 63, w = t >> 6;

    u16* As0 = (u16*)shm;
    u16* As1 = (u16*)(shm + 8192);
    u16* As2 = (u16*)(shm + 16384);
    u16* Bs0 = (u16*)(shm + 24576);
    u16* Bs1 = (u16*)(shm + 32768);
    u16* Bs2 = (u16*)(shm + 40960);

    // ---- XCD-aware bijective remap (m204): hw flat id -> contiguous logical chunk per XCD
    const int nwg = gridDim.x * gridDim.y;
    const int fid = blockIdx.x + gridDim.x * blockIdx.y;
    int logical;
    {
        const int q = nwg >> 3, r = nwg & 7;
        const int xcd = fid & 7, ix = fid >> 3;
        logical = (xcd < r ? xcd * (q + 1) : r * (q + 1) + (xcd - r) * q) + ix;
    }
    const int gy = gridDim.y;
    const int grp = logical / gy;            // group of 2 consecutive m-tiles
    const int hd_ = logical - grp * gy;
    const int n0 = hd_ * 128;

    const int wm = (w >> 1) * 64, wn = (w & 1) * 64;

    // ---- staging geometry: wave w owns rows [32w, 32w+32), 2 chunks of 16 rows.
    // LDS linear [128][32] u16; content slot-swizzled: LDS(row, sa) = G(row, sa ^ ((row>>1)&3)).
    const int rl0 = w * 32 + (l >> 2);
    const int rl1 = rl0 + 16;
    const int gso = 8 * ((l & 3) ^ ((l >> 3) & 3));    // swizzled 16B slot in source row
    const u16* pB0 = Bt + (size_t)min(n0 + rl0, N - 1) * K + gso;   // n0 fixed per block
    const u16* pB1 = Bt + (size_t)min(n0 + rl1, N - 1) * K + gso;
    const int wbase = (w * 32) * 32;                   // wave-uniform LDS elem offset

    // ---- fragment-read offsets (apply the same swizzle)
    const int rs = ((l & 15) >> 1) & 3;
    const int roff = 8 * ((l >> 4) ^ rs);              // u16 elems within the 32-elem row

    const int ns = K >> 5;                 // K-steps of 32 (>=3 for all our shapes)

    for (int it = 0; it < 2; ++it) {
        const int mtile = grp * 2 + it;
        const int m0 = mtile * 128;
        if (m0 >= M) break;                // uniform per block
        if (it) __syncthreads();           // protect prior epilogue's LDS aliases

        const u16* pA0 = A + (size_t)min(m0 + rl0, M - 1) * K + gso;
        const u16* pA1 = A + (size_t)min(m0 + rl1, M - 1) * K + gso;

        f32x4 acc[4][4];
        f32x4 z4 = {0.f, 0.f, 0.f, 0.f};
#pragma unroll
        for (int i = 0; i < 4; i++)
#pragma unroll
            for (int j = 0; j < 4; j++) acc[i][j] = z4;

        auto STAGE = [&](u16* As_, u16* Bs_, int k0) {
            gload16(pA0 + k0, As_ + wbase);
            gload16(pA1 + k0, As_ + wbase + 16 * 32);
            gload16(pB0 + k0, Bs_ + wbase);
            gload16(pB1 + k0, Bs_ + wbase + 16 * 32);
        };
        auto COMP = [&](const u16* As_, const u16* Bs_) {
            bf16x8 af[4], bfr[4];
#pragma unroll
            for (int i = 0; i < 4; i++) {
                af[i]  = *(const bf16x8*)(As_ + (wm + i * 16 + (l & 15)) * 32 + roff);
                bfr[i] = *(const bf16x8*)(Bs_ + (wn + i * 16 + (l & 15)) * 32 + roff);
            }
            __builtin_amdgcn_s_setprio(1);
#pragma unroll
            for (int i = 0; i < 4; i++)
#pragma unroll
                for (int j = 0; j < 4; j++)
                    acc[i][j] = __builtin_amdgcn_mfma_f32_16x16x32_bf16(af[i], bfr[j], acc[i][j], 0, 0, 0);
            __builtin_amdgcn_s_setprio(0);
        };
        auto WSEL = [&](int s_) {
            int ahead = ns - 1 - s_;                   // tiles staged beyond s (<=2)
            if (ahead >= 2)      asm volatile("s_waitcnt vmcnt(8)" ::: "memory");
            else if (ahead == 1) asm volatile("s_waitcnt vmcnt(4)" ::: "memory");
            else                 asm volatile("s_waitcnt vmcnt(0)" ::: "memory");
        };

        STAGE(As0, Bs0, 0);
        STAGE(As1, Bs1, 32);
        STAGE(As2, Bs2, 64);
        int s = 0;
        while (true) {
            WSEL(s); __builtin_amdgcn_s_barrier();
            COMP(As0, Bs0); __builtin_amdgcn_s_barrier();
            if (s + 3 < ns) STAGE(As0, Bs0, (s + 3) << 5);
            if (++s >= ns) break;
            WSEL(s); __builtin_amdgcn_s_barrier();
            COMP(As1, Bs1); __builtin_amdgcn_s_barrier();
            if (s + 3 < ns) STAGE(As1, Bs1, (s + 3) << 5);
            if (++s >= ns) break;
            WSEL(s); __builtin_amdgcn_s_barrier();
            COMP(As2, Bs2); __builtin_amdgcn_s_barrier();
            if (s + 3 < ns) STAGE(As2, Bs2, (s + 3) << 5);
            if (++s >= ns) break;
        }
        // all waves passed the final barrier; LDS arena free for epilogues.

        if (act == 2) {
            // fused classifier epilogue: z = relu(acc + bias); logits = z . Wc2 + bc2
            float* wl = (float*)shm;               // 1280 floats Wc2 + 10 bc2
            float (*logbuf)[128][10] = (float (*)[128][10])(shm + 8192);  // 10240 B
            for (int i = t; i < 1280; i += 256) wl[i] = Wc2[i];
            if (t < 10) wl[1280 + t] = bc2[t];
            __syncthreads();
            int cj[4];
#pragma unroll
            for (int j = 0; j < 4; j++) cj[j] = wn + j * 16 + (l & 15);
#pragma unroll
            for (int i = 0; i < 4; i++) {
#pragma unroll
                for (int r = 0; r < 4; r++) {
                    float zv[4];
#pragma unroll
                    for (int j = 0; j < 4; j++) {
                        float v = acc[i][j][r] + (bias ? bias[cj[j]] : 0.f);
                        zv[j] = v > 0.f ? v : 0.f;
                    }
                    float part[10];
#pragma unroll
                    for (int k = 0; k < 10; k++) {
                        float s2 = 0.f;
#pragma unroll
                        for (int j = 0; j < 4; j++) s2 += zv[j] * wl[cj[j] * 10 + k];
#pragma unroll
                        for (int o = 1; o < 16; o <<= 1) s2 += __shfl_xor(s2, o);
                        part[k] = s2;
                    }
                    if ((l & 15) == 0) {
                        int rl = wm + i * 16 + (l >> 4) * 4 + r;
#pragma unroll
                        for (int k = 0; k < 10; k++) logbuf[w & 1][rl][k] = part[k];
                    }
                }
            }
            __syncthreads();
            if (t < 128) {
                int row = m0 + t;
                if (row < M) {
#pragma unroll
                    for (int k = 0; k < 10; k++)
                        outp[(size_t)row * 10 + k] =
                            logbuf[0][t][k] + logbuf[1][t][k] + wl[1280 + k];
                }
            }
            continue;   // next m-tile
        }

#pragma unroll
        for (int i = 0; i < 4; i++) {
            int rbase = m0 + wm + i * 16 + (l >> 4) * 4;
#pragma unroll
            for (int j = 0; j < 4; j++) {
                int c = n0 + wn + j * 16 + (l & 15);
                float bv = bias ? bias[c] : 0.f;
#pragma unroll
                for (int r = 0; r < 4; r++) {
                    int row = rbase + r;
                    if (row < M) {
                        float v = acc[i][j][r] + bv;
                        if (act == 1) v = v > 0.f ? v : 0.f;
                        C[(size_t)row * N + c] = f2b(v);
                    }
                }
            }
        }

        if (aS) {   // fused alpha epilogue; head hd = n0/128
            float (*red)[128][2] = (float (*)[128][2])shm;   // alias arena
            const int hd = n0 >> 7;
            float aSv[4], aDv[4];
#pragma unroll
            for (int j = 0; j < 4; j++) {
                int c = n0 + wn + j * 16 + (l & 15);
                aSv[j] = aS[c];
                aDv[j] = aD[c];
            }
#pragma unroll
            for (int i = 0; i < 4; i++) {
#pragma unroll
                for (int r = 0; r < 4; r++) {
                    float vs = 0.f, vd = 0.f;
#pragma unroll
                    for (int j = 0; j < 4; j++) {
                        float hv = acc[i][j][r];
                        vs += hv * aSv[j];
                        vd += hv * aDv[j];
                    }
#pragma unroll
                    for (int o = 1; o < 16; o <<= 1) {
                        vs += __shfl_xor(vs, o);
                        vd += __shfl_xor(vd, o);
                    }
                    if ((l & 15) == 0) {
                        int rl = wm + i * 16 + (l >> 4) * 4 + r;
                        red[w & 1][rl][0] = vs;
                        red[w & 1][rl][1] = vd;
                    }
                }
            }
            __syncthreads();
            if (t < 128) {
                int row = m0 + t;
                if (row < M) {
                    asr[row * 4 + hd] = red[0][t][0] + red[1][t][0];
                    ads[row * 4 + hd] = red[0][t][1] + red[1][t][1];
                }
            }
        }
    }
}

__global__ __launch_bounds__(256) void BaselineGAT_41764261987077_kernel(
    int phase, int aux,
    const float* x, const int* ei,
    const float* W1, const float* as1, const float* ad1, const float* b1,
    const float* W2, const float* as2, const float* ad2, const float* b2,
    const float* Wc1, const float* bc1, const float* Wc2, const float* bc2,
    float* out,
    u16* hAb, u16* hbB, float* asr, float* ads,
    u16* xb, u16* w1t, u16* w2t, u16* wc1t,
    int* flag, int* cnt, int* tmp, int* bsum, int* boff,
    int* rowptr, int* cursor, int* col,
    const u16* gA, const u16* gB, u16* gC, const float* gBias,
    const float* gAs, const float* gAd,
    int gM, int gN, int gK, int gAct,
    int NODES, int E, int nblk)
{
    // 4KB static (scan/flag buffers) + dynamic GEMM arena (48KB on phase-30 launches only)
    __shared__ int sstat[1024];
    extern __shared__ char dynshm[];
    int* smi = sstat;                 // phases 0,3 (uses [0..256])
    int* smb = sstat + 512;           // phase 5 lookback scan

    const int t = threadIdx.x;
    const int gid = blockIdx.x * 256 + t;
    const int EN = E + NODES;

    switch (phase) {
    case 100: {   // ws-sentinel paint only
        if (gid < NODES * 10) out[gid] = 1000.0f;
    } break;
    case 0: {     // block 0: edge dtype detect; other blocks: zero cnt
        if (blockIdx.x == 0) {
            if (t == 0) smi[256] = 0;
            __syncthreads();
            for (int j = t; j < 1024; j += 256)
                if (ei[2 * j + 1] != 0) atomicAdd(&smi[256], 1);
            __syncthreads();
            if (t == 0) flag[0] = (smi[256] < 16) ? 2 : 1;
        } else {
            int i = (blockIdx.x - 1) * 256 + t;
            if (i < NODES) cnt[i] = 0;
        }
    } break;
    case 2: {     // histogram of dst (+self loops)
        if (gid >= EN) return;
        int step = flag[0];
        int d;
        if (gid < E) {
            d = ei[(size_t)(E + gid) * step];
            if ((unsigned)d >= (unsigned)NODES) d = 0;
        } else d = gid - E;
        atomicAdd(&cnt[d], 1);
    } break;
    case 3: {     // block-local inclusive scan
        smi[t] = (gid < NODES) ? cnt[gid] : 0;
        __syncthreads();
        for (int o = 1; o < 256; o <<= 1) {
            int add = (t >= o) ? smi[t - o] : 0;
            __syncthreads();
            smi[t] += add;
            __syncthreads();
        }
        if (gid < NODES) tmp[gid] = smi[t];
        if (t == 255) bsum[blockIdx.x] = smi[255];
    } break;
    case 5: {     // rowptr + cursor, with inline lookback scan of bsum
        smb[t] = (t < nblk) ? bsum[t] : 0;
        __syncthreads();
        for (int o = 1; o < 256; o <<= 1) {
            int add = (t >= o) ? smb[t - o] : 0;
            __syncthreads();
            smb[t] += add;
            __syncthreads();
        }
        int base = (blockIdx.x == 0) ? 0 : smb[blockIdx.x - 1];
        if (gid >= NODES) return;
        int incl = tmp[gid] + base;
        rowptr[gid + 1] = incl;
        cursor[gid] = incl - cnt[gid];
        if (gid == 0) rowptr[0] = 0;
    } break;
    case 6: {
        if (gid >= EN) return;
        int step = flag[0];
        int d, s;
        if (gid < E) {
            s = ei[(size_t)gid * step];
            d = ei[(size_t)(E + gid) * step];
            if ((unsigned)s >= (unsigned)NODES) s = 0;
            if ((unsigned)d >= (unsigned)NODES) d = 0;
        } else { d = gid - E; s = d; }
        int pos = atomicAdd(&cursor[d], 1);
        col[pos] = s;
    } break;
    case 20: {    // conversions: vectorized x (8 elems/thread) + scalar weights
        int i = gid;
        const int XC = NODES * 44;            // 8-elem chunks of xb rows (352/8)
        if (i < XC) {
            int n = i / 44, kk = (i - n * 44) * 8;
            short8 o;
            if (kk < 336) {
                const f32x4* xp = (const f32x4*)(x + (size_t)n * 336 + kk);
                f32x4 f0 = xp[0], f1 = xp[1];
                o[0] = (short)f2b(f0[0]); o[1] = (short)f2b(f0[1]);
                o[2] = (short)f2b(f0[2]); o[3] = (short)f2b(f0[3]);
                o[4] = (short)f2b(f1[0]); o[5] = (short)f2b(f1[1]);
                o[6] = (short)f2b(f1[2]); o[7] = (short)f2b(f1[3]);
            } else {
#pragma unroll
                for (int e = 0; e < 8; e++) o[e] = 0;
            }
            *(short8*)(xb + (size_t)n * 352 + kk) = o;
            return;
        }
        i -= XC;
        if (i < 512 * 352) {          // W1 [336,512] -> w1t [512,352] T+pad
            int n = i / 352, k = i - n * 352;
            w1t[i] = (k < 336) ? f2b(W1[(size_t)k * 512 + n]) : (u16)0;
            return;
        }
        i -= 512 * 352;
        if (i < 512 * 512) {          // W2 [512,512] -> w2t [512,512] T
            int n = i >> 9, k = i & 511;
            w2t[i] = f2b(W2[(size_t)k * 512 + n]);
            return;
        }
        i -= 512 * 512;
        if (i < 128 * 512) {          // Wc1 [512,128] -> wc1t [128,512] T
            int n = i >> 9, k = i & 511;
            wc1t[i] = f2b(Wc1[(size_t)k * 128 + n]);
        }
    } break;
    case 30: gemm_dev(gA, gB, gC, gBias, gAs, gAd, asr, ads,
                      Wc2, bc2, out, gM, gN, gK, gAct, dynshm); break;
    case 31: agg_dev(rowptr, col, asr, ads, hAb, gBias, hbB, aux, NODES); break;
    }
}

extern "C" void kernel_launch(void* const* d_in, const int* in_sizes, int n_in,
                              void* d_out, int out_size, void* d_ws, size_t ws_size,
                              hipStream_t stream) {
    const float* x   = (const float*)d_in[0];
    const int*   ei  = (const int*)d_in[1];
    const float* W1  = (const float*)d_in[2];
    const float* as1 = (const float*)d_in[3];
    const float* ad1 = (const float*)d_in[4];
    const float* b1  = (const float*)d_in[5];
    const float* W2  = (const float*)d_in[6];
    const float* as2 = (const float*)d_in[7];
    const float* ad2 = (const float*)d_in[8];
    const float* b2  = (const float*)d_in[9];
    const float* Wc1 = (const float*)d_in[10];
    const float* bc1 = (const float*)d_in[11];
    const float* Wc2 = (const float*)d_in[12];
    const float* bc2 = (const float*)d_in[13];

    const int NODES = in_sizes[0] / 336;   // 50000
    const int E     = in_sizes[1] / 2;     // 500000

    char* ws = (char*)d_ws;
    size_t off = 0;
    auto alloc = [&](size_t b) -> char* {
        char* p = ws + off; off = (off + b + 255) & ~(size_t)255; return p;
    };
    u16*   xb   = (u16*)alloc((size_t)NODES * 352 * 2);
    u16*   hAb  = (u16*)alloc((size_t)NODES * 512 * 2);   // GEMM out (bf16)
    u16*   hbB  = (u16*)alloc((size_t)NODES * 512 * 2);   // agg out (bf16)
    float* asr  = (float*)alloc((size_t)NODES * 4 * 4);
    float* ads  = (float*)alloc((size_t)NODES * 4 * 4);
    u16*   w1t  = (u16*)alloc((size_t)512 * 352 * 2);
    u16*   w2t  = (u16*)alloc((size_t)512 * 512 * 2);
    u16*   wc1t = (u16*)alloc((size_t)128 * 512 * 2);
    int* flag   = (int*)alloc(256);
    int* cnt    = (int*)alloc((size_t)NODES * 4);
    int* tmp    = (int*)alloc((size_t)NODES * 4);
    int* bsum   = (int*)alloc(4096);
    int* boff   = (int*)alloc(4096);
    int* rowptr = (int*)alloc((size_t)(NODES + 1) * 4);
    int* cursor = (int*)alloc((size_t)NODES * 4);
    int* col    = (int*)alloc((size_t)(E + NODES) * 4);

    const int nblk = (NODES + 255) / 256;
    const int eblk = (E + NODES + 255) / 256;
    const int oblk = (out_size + 255) / 256;
    const int mt   = (NODES + 127) / 128;      // 391 m-tiles
    const int mtg  = (mt + 1) / 2;             // 196 groups of 2 m-tiles
    const int cvt_total = NODES * 44 + 512 * 352 + 512 * 512 + 128 * 512;

    auto L = [&](int phase, int aux, dim3 grid, size_t shmem,
                 const u16* gA = nullptr, const u16* gB = nullptr,
                 u16* gC = nullptr, const float* gBias = nullptr,
                 const float* gAs = nullptr, const float* gAd = nullptr,
                 int gM = 0, int gN = 0, int gK = 0, int gAct = 0) {
        BaselineGAT_41764261987077_kernel<<<grid, 256, shmem, stream>>>(
            phase, aux, x, ei, W1, as1, ad1, b1, W2, as2, ad2, b2,
            Wc1, bc1, Wc2, bc2, (float*)d_out,
            hAb, hbB, asr, ads, xb, w1t, w2t, wc1t,
            flag, cnt, tmp, bsum, boff, rowptr, cursor, col,
            gA, gB, gC, gBias, gAs, gAd, gM, gN, gK, gAct,
            NODES, E, nblk);
    };
    const size_t GSH = 49152;   // GEMM dynamic arena: 3x(8KB A + 8KB B)

    if (n_in < 14 || off > ws_size) { L(100, 1, oblk, 0); return; }

    // CSR build (detect+zero merged; scan2 folded into phase 5 lookback)
    L(0, 0, nblk + 1, 0);
    L(2, 0, eblk, 0);
    L(3, 0, nblk, 0);
    L(5, 0, nblk, 0);
    L(6, 0, eblk, 0);

    // bf16 conversions (vectorized x path)
    L(20, 0, (cvt_total + 255) / 256, 0);

    // layer 1: h1 = xb @ w1t^T (bf16) + fused alpha, agg(elu) -> hbB
    L(30, 0, dim3(mtg, 4), GSH, xb, w1t, hAb, nullptr, as1, ad1, NODES, 512, 352, 0);
    L(31, 1, 4096, 0, nullptr, nullptr, nullptr, b1);      // persistent-wave agg

    // layer 2
    L(30, 0, dim3(mtg, 4), GSH, hbB, w2t, hAb, nullptr, as2, ad2, NODES, 512, 512, 0);
    L(31, 0, 4096, 0, nullptr, nullptr, nullptr, b2);

    // classifier fused: relu(hbB @ wc1t^T + bc1) . Wc2 + bc2 -> out (fp32)
    L(30, 0, dim3(mtg, 1), GSH, hbB, wc1t, nullptr, bc1, nullptr, nullptr, NODES, 128, 512, 2);
}

// Round 6
// 569.699 us; speedup vs baseline: 1.0482x; 1.0482x over previous
//
#include <hip/hip_runtime.h>
#include <math.h>

typedef unsigned short u16;
typedef unsigned int u32;
typedef short short8 __attribute__((ext_vector_type(8)));
typedef __bf16 bf16x8 __attribute__((ext_vector_type(8)));
typedef float f32x4 __attribute__((ext_vector_type(4)));
typedef u32 u32x4 __attribute__((ext_vector_type(4)));

typedef const __attribute__((address_space(1))) void* as1cv;
typedef __attribute__((address_space(3))) void* as3v;

__device__ __forceinline__ void gload16(const void* g, void* l) {
    // async global->LDS DMA, 16B/lane; LDS dest = uniform base + lane*16
    __builtin_amdgcn_global_load_lds((as1cv)g, (as3v)l, 16, 0, 0);
}

__device__ __forceinline__ float b2f(u16 u) {
    union { u32 i; float f; } v; v.i = ((u32)u) << 16; return v.f;
}
__device__ __forceinline__ float b2f_lo(u32 q) {
    union { u32 i; float f; } v; v.i = q << 16; return v.f;
}
__device__ __forceinline__ float b2f_hi(u32 q) {
    union { u32 i; float f; } v; v.i = q & 0xffff0000u; return v.f;
}
__device__ __forceinline__ u16 f2b(float f) {
    union { float f; u32 i; } v; v.f = f;
    u32 i = v.i;
    u32 r = (i + 0x7fffu + ((i >> 16) & 1u)) >> 16;   // RNE fp32 -> bf16
    return (u16)r;
}
__device__ __forceinline__ u32 pack2(u16 a, u16 b) { return (u32)a | ((u32)b << 16); }

// ---------- device helpers (all phases live in the ONE named kernel) ----------

// segment softmax + aggregate. Persistent waves (grid 4096 blocks = 16K waves);
// lane l owns channels 8l..8l+7 (head = l>>4). No max-subtraction (|e| small).
// v3: exact tail — full 8-groups, one 4-group, <=3 singles. No clamped duplicate
// gathers (was ~+30% gather instructions at mean degree 11), no post-exp mask.
// Wave-uniform indices via readfirstlane (SGPR gather bases, scalar col loads).
__device__ void agg_dev(const int* __restrict__ rowptr, const int* __restrict__ col,
                        const float* __restrict__ asrc, const float* __restrict__ adst,
                        const u16* __restrict__ hb, const float* __restrict__ bias,
                        u16* __restrict__ outb, int elu, int NODES) {
    const int wid = __builtin_amdgcn_readfirstlane((blockIdx.x * 256 + threadIdx.x) >> 6);
    const int nwaves = gridDim.x << 2;
    const int l = threadIdx.x & 63;
    const int hd = l >> 4;
    const int cbase = 8 * l;
    float bv[8];
#pragma unroll
    for (int c = 0; c < 8; c++) bv[c] = bias[cbase + c];

    for (int n = wid; n < NODES; n += nwaves) {
        const int beg = __builtin_amdgcn_readfirstlane(rowptr[n]);
        const int end = __builtin_amdgcn_readfirstlane(rowptr[n + 1]);
        const float ad = adst[n * 4 + hd];
        float acc0[8], acc1[8];
#pragma unroll
        for (int c = 0; c < 8; c++) { acc0[c] = 0.f; acc1[c] = 0.f; }
        float ss0 = 0.f, ss1 = 0.f;
        int j = beg;
        for (; j + 8 <= end; j += 8) {             // full 8-groups (8 gathers in flight)
            int s[8];
#pragma unroll
            for (int q = 0; q < 8; q++) s[q] = __builtin_amdgcn_readfirstlane(col[j + q]);
            u32x4 g[8];
#pragma unroll
            for (int q = 0; q < 8; q++)
                g[q] = *(const u32x4*)(hb + (size_t)s[q] * 512 + cbase);
            float p[8];
#pragma unroll
            for (int q = 0; q < 8; q++) {
                float e = asrc[(size_t)s[q] * 4 + hd] + ad;
                e = e > 0.f ? e : 0.2f * e;
                p[q] = __expf(e);
            }
#pragma unroll
            for (int q = 0; q < 8; q += 2) {
                ss0 += p[q]; ss1 += p[q + 1];
#pragma unroll
                for (int u = 0; u < 4; u++) {
                    acc0[2 * u]     += p[q]     * b2f_lo(g[q][u]);
                    acc0[2 * u + 1] += p[q]     * b2f_hi(g[q][u]);
                    acc1[2 * u]     += p[q + 1] * b2f_lo(g[q + 1][u]);
                    acc1[2 * u + 1] += p[q + 1] * b2f_hi(g[q + 1][u]);
                }
            }
        }
        if (j + 4 <= end) {                        // one 4-group
            int s[4];
#pragma unroll
            for (int q = 0; q < 4; q++) s[q] = __builtin_amdgcn_readfirstlane(col[j + q]);
            u32x4 g[4];
#pragma unroll
            for (int q = 0; q < 4; q++)
                g[q] = *(const u32x4*)(hb + (size_t)s[q] * 512 + cbase);
            float p[4];
#pragma unroll
            for (int q = 0; q < 4; q++) {
                float e = asrc[(size_t)s[q] * 4 + hd] + ad;
                e = e > 0.f ? e : 0.2f * e;
                p[q] = __expf(e);
            }
#pragma unroll
            for (int q = 0; q < 4; q += 2) {
                ss0 += p[q]; ss1 += p[q + 1];
#pragma unroll
                for (int u = 0; u < 4; u++) {
                    acc0[2 * u]     += p[q]     * b2f_lo(g[q][u]);
                    acc0[2 * u + 1] += p[q]     * b2f_hi(g[q][u]);
                    acc1[2 * u]     += p[q + 1] * b2f_lo(g[q + 1][u]);
                    acc1[2 * u + 1] += p[q + 1] * b2f_hi(g[q + 1][u]);
                }
            }
            j += 4;
        }
        for (; j < end; ++j) {                     // <=3 singles
            int s0 = __builtin_amdgcn_readfirstlane(col[j]);
            u32x4 g0 = *(const u32x4*)(hb + (size_t)s0 * 512 + cbase);
            float e = asrc[(size_t)s0 * 4 + hd] + ad;
            e = e > 0.f ? e : 0.2f * e;
            float p0 = __expf(e);
            ss0 += p0;
#pragma unroll
            for (int u = 0; u < 4; u++) {
                acc0[2 * u]     += p0 * b2f_lo(g0[u]);
                acc0[2 * u + 1] += p0 * b2f_hi(g0[u]);
            }
        }
        float inv = 1.f / (ss0 + ss1 + 1e-16f);
        float v[8];
#pragma unroll
        for (int c = 0; c < 8; c++) {
            float tv = (acc0[c] + acc1[c]) * inv + bv[c];
            if (elu) tv = tv > 0.f ? tv : expm1f(tv);
            v[c] = tv;
        }
        u32x4 ov;
        ov[0] = pack2(f2b(v[0]), f2b(v[1]));
        ov[1] = pack2(f2b(v[2]), f2b(v[3]));
        ov[2] = pack2(f2b(v[4]), f2b(v[5]));
        ov[3] = pack2(f2b(v[6]), f2b(v[7]));
        *(u32x4*)(outb + (size_t)n * 512 + cbase) = ov;
    }
}

// MFMA GEMM: acc = A bf16[M,K] @ Bt bf16[N,K]^T, fp32 accum.
// 128x128 tile, 4 waves 2x2, K multiple of 32 (>=96).
// v5 (reverted from v6's 2-tile regression — VGPR 100->120 hurt all phases):
//     3-buffer lead-3 pipeline, counted vmcnt (never 0 in loop), raw s_barrier,
//     source-swizzled gload_lds staging (conflict-free ds_read_b128), bijective
//     XCD-chunk remap. LDS arena DYNAMIC (48KB on phase-30 launches only).
// act 0: store C bf16.  act 1: relu(+bias), store C bf16.
// act 2: relu(+bias), NO C store; fused logits: out[row,k] = z-row . Wc2 + bc2.
// aS != nullptr (with act 0): fused alpha epilogue (stores C too).
__device__ void gemm_dev(const u16* __restrict__ A, const u16* __restrict__ Bt,
                         u16* __restrict__ C, const float* __restrict__ bias,
                         const float* __restrict__ aS, const float* __restrict__ aD,
                         float* __restrict__ asr, float* __restrict__ ads,
                         const float* __restrict__ Wc2, const float* __restrict__ bc2,
                         float* __restrict__ outp,
                         int M, int N, int K, int act, char* shm) {
    const int t = threadIdx.x;
    const int l = t & 63, w = t >> 6;

    u16* As0 = (u16*)shm;
    u16* As1 = (u16*)(shm + 8192);
    u16* As2 = (u16*)(shm + 16384);
    u16* Bs0 = (u16*)(shm + 24576);
    u16* Bs1 = (u16*)(shm + 32768);
    u16* Bs2 = (u16*)(shm + 40960);

    // ---- XCD-aware bijective remap (m204): hw flat id -> contiguous logical chunk per XCD
    const int nwg = gridDim.x * gridDim.y;
    const int fid = blockIdx.x + gridDim.x * blockIdx.y;
    int logical;
    {
        const int q = nwg >> 3, r = nwg & 7;
        const int xcd = fid & 7, ix = fid >> 3;
        logical = (xcd < r ? xcd * (q + 1) : r * (q + 1) + (xcd - r) * q) + ix;
    }
    const int gy = gridDim.y;
    const int mtile = logical / gy;          // adjacent logicals share mtile (A panel reuse)
    const int hd_ = logical - mtile * gy;
    const int m0 = mtile * 128, n0 = hd_ * 128;

    const int wm = (w >> 1) * 64, wn = (w & 1) * 64;

    // ---- staging: wave w owns rows [32w, 32w+32) of both tiles, 2 chunks of 16 rows.
    // LDS linear [128][32] u16; content slot-swizzled: LDS(row, sa) = G(row, sa ^ ((row>>1)&3)).
    const int rl0 = w * 32 + (l >> 2);
    const int rl1 = rl0 + 16;
    const int gso = 8 * ((l & 3) ^ ((l >> 3) & 3));    // swizzled 16B slot in source row
    const u16* pA0 = A + (size_t)min(m0 + rl0, M - 1) * K + gso;
    const u16* pA1 = A + (size_t)min(m0 + rl1, M - 1) * K + gso;
    const u16* pB0 = Bt + (size_t)min(n0 + rl0, N - 1) * K + gso;
    const u16* pB1 = Bt + (size_t)min(n0 + rl1, N - 1) * K + gso;
    const int wbase = (w * 32) * 32;                   // wave-uniform LDS elem offset

    // ---- fragment-read offsets (apply the same swizzle)
    const int rs = ((l & 15) >> 1) & 3;
    const int roff = 8 * ((l >> 4) ^ rs);              // u16 elems within the 32-elem row

    f32x4 acc[4][4];
    f32x4 z4 = {0.f, 0.f, 0.f, 0.f};
#pragma unroll
    for (int i = 0; i < 4; i++)
#pragma unroll
        for (int j = 0; j < 4; j++) acc[i][j] = z4;

    auto STAGE = [&](u16* As_, u16* Bs_, int k0) {
        gload16(pA0 + k0, As_ + wbase);
        gload16(pA1 + k0, As_ + wbase + 16 * 32);
        gload16(pB0 + k0, Bs_ + wbase);
        gload16(pB1 + k0, Bs_ + wbase + 16 * 32);
    };
    auto COMP = [&](const u16* As_, const u16* Bs_) {
        bf16x8 af[4], bfr[4];
#pragma unroll
        for (int i = 0; i < 4; i++) {
            af[i]  = *(const bf16x8*)(As_ + (wm + i * 16 + (l & 15)) * 32 + roff);
            bfr[i] = *(const bf16x8*)(Bs_ + (wn + i * 16 + (l & 15)) * 32 + roff);
        }
        __builtin_amdgcn_s_setprio(1);
#pragma unroll
        for (int i = 0; i < 4; i++)
#pragma unroll
            for (int j = 0; j < 4; j++)
                acc[i][j] = __builtin_amdgcn_mfma_f32_16x16x32_bf16(af[i], bfr[j], acc[i][j], 0, 0, 0);
        __builtin_amdgcn_s_setprio(0);
    };
    auto WSEL = [&](int s_, int ns_) {
        int ahead = ns_ - 1 - s_;                      // tiles staged beyond s (<=2)
        if (ahead >= 2)      asm volatile("s_waitcnt vmcnt(8)" ::: "memory");
        else if (ahead == 1) asm volatile("s_waitcnt vmcnt(4)" ::: "memory");
        else                 asm volatile("s_waitcnt vmcnt(0)" ::: "memory");
    };

    const int ns = K >> 5;                 // K-steps of 32 (ns >= 3 for all our shapes)
    STAGE(As0, Bs0, 0);
    STAGE(As1, Bs1, 32);
    STAGE(As2, Bs2, 64);
    int s = 0;
    while (true) {
        WSEL(s, ns); __builtin_amdgcn_s_barrier();
        COMP(As0, Bs0); __builtin_amdgcn_s_barrier();
        if (s + 3 < ns) STAGE(As0, Bs0, (s + 3) << 5);
        if (++s >= ns) break;
        WSEL(s, ns); __builtin_amdgcn_s_barrier();
        COMP(As1, Bs1); __builtin_amdgcn_s_barrier();
        if (s + 3 < ns) STAGE(As1, Bs1, (s + 3) << 5);
        if (++s >= ns) break;
        WSEL(s, ns); __builtin_amdgcn_s_barrier();
        COMP(As2, Bs2); __builtin_amdgcn_s_barrier();
        if (s + 3 < ns) STAGE(As2, Bs2, (s + 3) << 5);
        if (++s >= ns) break;
    }
    // all waves passed the final barrier; LDS arena is free for epilogues.

    if (act == 2) {
        // fused classifier epilogue: z = relu(acc + bias); logits = z . Wc2 + bc2
        float* wl = (float*)shm;               // 1280 floats Wc2 + 10 bc2
        float (*logbuf)[128][10] = (float (*)[128][10])(shm + 8192);  // 10240 B
        for (int i = t; i < 1280; i += 256) wl[i] = Wc2[i];
        if (t < 10) wl[1280 + t] = bc2[t];
        __syncthreads();
        int cj[4];
#pragma unroll
        for (int j = 0; j < 4; j++) cj[j] = wn + j * 16 + (l & 15);
#pragma unroll
        for (int i = 0; i < 4; i++) {
#pragma unroll
            for (int r = 0; r < 4; r++) {
                float zv[4];
#pragma unroll
                for (int j = 0; j < 4; j++) {
                    float v = acc[i][j][r] + (bias ? bias[cj[j]] : 0.f);
                    zv[j] = v > 0.f ? v : 0.f;
                }
                float part[10];
#pragma unroll
                for (int k = 0; k < 10; k++) {
                    float s2 = 0.f;
#pragma unroll
                    for (int j = 0; j < 4; j++) s2 += zv[j] * wl[cj[j] * 10 + k];
#pragma unroll
                    for (int o = 1; o < 16; o <<= 1) s2 += __shfl_xor(s2, o);
                    part[k] = s2;
                }
                if ((l & 15) == 0) {
                    int rl = wm + i * 16 + (l >> 4) * 4 + r;
#pragma unroll
                    for (int k = 0; k < 10; k++) logbuf[w & 1][rl][k] = part[k];
                }
            }
        }
        __syncthreads();
        if (t < 128) {
            int row = m0 + t;
            if (row < M) {
#pragma unroll
                for (int k = 0; k < 10; k++)
                    outp[(size_t)row * 10 + k] =
                        logbuf[0][t][k] + logbuf[1][t][k] + wl[1280 + k];
            }
        }
        return;
    }

#pragma unroll
    for (int i = 0; i < 4; i++) {
        int rbase = m0 + wm + i * 16 + (l >> 4) * 4;
#pragma unroll
        for (int j = 0; j < 4; j++) {
            int c = n0 + wn + j * 16 + (l & 15);
            float bv = bias ? bias[c] : 0.f;
#pragma unroll
            for (int r = 0; r < 4; r++) {
                int row = rbase + r;
                if (row < M) {
                    float v = acc[i][j][r] + bv;
                    if (act == 1) v = v > 0.f ? v : 0.f;
                    C[(size_t)row * N + c] = f2b(v);
                }
            }
        }
    }

    if (aS) {   // fused alpha epilogue; head hd = n0/128
        float (*red)[128][2] = (float (*)[128][2])shm;   // alias arena (free after loop)
        const int hd = n0 >> 7;
        float aSv[4], aDv[4];
#pragma unroll
        for (int j = 0; j < 4; j++) {
            int c = n0 + wn + j * 16 + (l & 15);
            aSv[j] = aS[c];
            aDv[j] = aD[c];
        }
#pragma unroll
        for (int i = 0; i < 4; i++) {
#pragma unroll
            for (int r = 0; r < 4; r++) {
                float vs = 0.f, vd = 0.f;
#pragma unroll
                for (int j = 0; j < 4; j++) {
                    float hv = acc[i][j][r];
                    vs += hv * aSv[j];
                    vd += hv * aDv[j];
                }
#pragma unroll
                for (int o = 1; o < 16; o <<= 1) {
                    vs += __shfl_xor(vs, o);
                    vd += __shfl_xor(vd, o);
                }
                if ((l & 15) == 0) {
                    int rl = wm + i * 16 + (l >> 4) * 4 + r;
                    red[w & 1][rl][0] = vs;
                    red[w & 1][rl][1] = vd;
                }
            }
        }
        __syncthreads();
        if (t < 128) {
            int row = m0 + t;
            if (row < M) {
                asr[row * 4 + hd] = red[0][t][0] + red[1][t][0];
                ads[row * 4 + hd] = red[0][t][1] + red[1][t][1];
            }
        }
    }
}

__global__ __launch_bounds__(256) void BaselineGAT_41764261987077_kernel(
    int phase, int aux,
    const float* x, const int* ei,
    const float* W1, const float* as1, const float* ad1, const float* b1,
    const float* W2, const float* as2, const float* ad2, const float* b2,
    const float* Wc1, const float* bc1, const float* Wc2, const float* bc2,
    float* out,
    u16* hAb, u16* hbB, float* asr, float* ads,
    u16* xb, u16* w1t, u16* w2t, u16* wc1t,
    int* flag, int* cnt, int* tmp, int* bsum, int* boff,
    int* rowptr, int* cursor, int* col,
    const u16* gA, const u16* gB, u16* gC, const float* gBias,
    const float* gAs, const float* gAd,
    int gM, int gN, int gK, int gAct,
    int NODES, int E, int nblk)
{
    // 4KB static (scan/flag buffers) + dynamic GEMM arena (48KB on phase-30 launches only)
    __shared__ int sstat[1024];
    extern __shared__ char dynshm[];
    int* smi = sstat;                 // phases 0,3 (uses [0..256])
    int* smb = sstat + 512;           // phase 5 lookback scan

    const int t = threadIdx.x;
    const int gid = blockIdx.x * 256 + t;
    const int EN = E + NODES;

    switch (phase) {
    case 100: {   // ws-sentinel paint only
        if (gid < NODES * 10) out[gid] = 1000.0f;
    } break;
    case 0: {     // block 0: edge dtype detect; other blocks: zero cnt
        if (blockIdx.x == 0) {
            if (t == 0) smi[256] = 0;
            __syncthreads();
            for (int j = t; j < 1024; j += 256)
                if (ei[2 * j + 1] != 0) atomicAdd(&smi[256], 1);
            __syncthreads();
            if (t == 0) flag[0] = (smi[256] < 16) ? 2 : 1;
        } else {
            int i = (blockIdx.x - 1) * 256 + t;
            if (i < NODES) cnt[i] = 0;
        }
    } break;
    case 2: {     // histogram of dst (+self loops)
        if (gid >= EN) return;
        int step = flag[0];
        int d;
        if (gid < E) {
            d = ei[(size_t)(E + gid) * step];
            if ((unsigned)d >= (unsigned)NODES) d = 0;
        } else d = gid - E;
        atomicAdd(&cnt[d], 1);
    } break;
    case 3: {     // block-local inclusive scan
        smi[t] = (gid < NODES) ? cnt[gid] : 0;
        __syncthreads();
        for (int o = 1; o < 256; o <<= 1) {
            int add = (t >= o) ? smi[t - o] : 0;
            __syncthreads();
            smi[t] += add;
            __syncthreads();
        }
        if (gid < NODES) tmp[gid] = smi[t];
        if (t == 255) bsum[blockIdx.x] = smi[255];
    } break;
    case 5: {     // rowptr + cursor, with inline lookback scan of bsum
        smb[t] = (t < nblk) ? bsum[t] : 0;
        __syncthreads();
        for (int o = 1; o < 256; o <<= 1) {
            int add = (t >= o) ? smb[t - o] : 0;
            __syncthreads();
            smb[t] += add;
            __syncthreads();
        }
        int base = (blockIdx.x == 0) ? 0 : smb[blockIdx.x - 1];
        if (gid >= NODES) return;
        int incl = tmp[gid] + base;
        rowptr[gid + 1] = incl;
        cursor[gid] = incl - cnt[gid];
        if (gid == 0) rowptr[0] = 0;
    } break;
    case 6: {
        if (gid >= EN) return;
        int step = flag[0];
        int d, s;
        if (gid < E) {
            s = ei[(size_t)gid * step];
            d = ei[(size_t)(E + gid) * step];
            if ((unsigned)s >= (unsigned)NODES) s = 0;
            if ((unsigned)d >= (unsigned)NODES) d = 0;
        } else { d = gid - E; s = d; }
        int pos = atomicAdd(&cursor[d], 1);
        col[pos] = s;
    } break;
    case 20: {    // conversions: vectorized x (8 elems/thread) + scalar weights
        int i = gid;
        const int XC = NODES * 44;            // 8-elem chunks of xb rows (352/8)
        if (i < XC) {
            int n = i / 44, kk = (i - n * 44) * 8;
            short8 o;
            if (kk < 336) {
                const f32x4* xp = (const f32x4*)(x + (size_t)n * 336 + kk);
                f32x4 f0 = xp[0], f1 = xp[1];
                o[0] = (short)f2b(f0[0]); o[1] = (short)f2b(f0[1]);
                o[2] = (short)f2b(f0[2]); o[3] = (short)f2b(f0[3]);
                o[4] = (short)f2b(f1[0]); o[5] = (short)f2b(f1[1]);
                o[6] = (short)f2b(f1[2]); o[7] = (short)f2b(f1[3]);
            } else {
#pragma unroll
                for (int e = 0; e < 8; e++) o[e] = 0;
            }
            *(short8*)(xb + (size_t)n * 352 + kk) = o;
            return;
        }
        i -= XC;
        if (i < 512 * 352) {          // W1 [336,512] -> w1t [512,352] T+pad
            int n = i / 352, k = i - n * 352;
            w1t[i] = (k < 336) ? f2b(W1[(size_t)k * 512 + n]) : (u16)0;
            return;
        }
        i -= 512 * 352;
        if (i < 512 * 512) {          // W2 [512,512] -> w2t [512,512] T
            int n = i >> 9, k = i & 511;
            w2t[i] = f2b(W2[(size_t)k * 512 + n]);
            return;
        }
        i -= 512 * 512;
        if (i < 128 * 512) {          // Wc1 [512,128] -> wc1t [128,512] T
            int n = i >> 9, k = i & 511;
            wc1t[i] = f2b(Wc1[(size_t)k * 128 + n]);
        }
    } break;
    case 30: gemm_dev(gA, gB, gC, gBias, gAs, gAd, asr, ads,
                      Wc2, bc2, out, gM, gN, gK, gAct, dynshm); break;
    case 31: agg_dev(rowptr, col, asr, ads, hAb, gBias, hbB, aux, NODES); break;
    }
}

extern "C" void kernel_launch(void* const* d_in, const int* in_sizes, int n_in,
                              void* d_out, int out_size, void* d_ws, size_t ws_size,
                              hipStream_t stream) {
    const float* x   = (const float*)d_in[0];
    const int*   ei  = (const int*)d_in[1];
    const float* W1  = (const float*)d_in[2];
    const float* as1 = (const float*)d_in[3];
    const float* ad1 = (const float*)d_in[4];
    const float* b1  = (const float*)d_in[5];
    const float* W2  = (const float*)d_in[6];
    const float* as2 = (const float*)d_in[7];
    const float* ad2 = (const float*)d_in[8];
    const float* b2  = (const float*)d_in[9];
    const float* Wc1 = (const float*)d_in[10];
    const float* bc1 = (const float*)d_in[11];
    const float* Wc2 = (const float*)d_in[12];
    const float* bc2 = (const float*)d_in[13];

    const int NODES = in_sizes[0] / 336;   // 50000
    const int E     = in_sizes[1] / 2;     // 500000

    char* ws = (char*)d_ws;
    size_t off = 0;
    auto alloc = [&](size_t b) -> char* {
        char* p = ws + off; off = (off + b + 255) & ~(size_t)255; return p;
    };
    u16*   xb   = (u16*)alloc((size_t)NODES * 352 * 2);
    u16*   hAb  = (u16*)alloc((size_t)NODES * 512 * 2);   // GEMM out (bf16)
    u16*   hbB  = (u16*)alloc((size_t)NODES * 512 * 2);   // agg out (bf16)
    float* asr  = (float*)alloc((size_t)NODES * 4 * 4);
    float* ads  = (float*)alloc((size_t)NODES * 4 * 4);
    u16*   w1t  = (u16*)alloc((size_t)512 * 352 * 2);
    u16*   w2t  = (u16*)alloc((size_t)512 * 512 * 2);
    u16*   wc1t = (u16*)alloc((size_t)128 * 512 * 2);
    int* flag   = (int*)alloc(256);
    int* cnt    = (int*)alloc((size_t)NODES * 4);
    int* tmp    = (int*)alloc((size_t)NODES * 4);
    int* bsum   = (int*)alloc(4096);
    int* boff   = (int*)alloc(4096);
    int* rowptr = (int*)alloc((size_t)(NODES + 1) * 4);
    int* cursor = (int*)alloc((size_t)NODES * 4);
    int* col    = (int*)alloc((size_t)(E + NODES) * 4);

    const int nblk = (NODES + 255) / 256;
    const int eblk = (E + NODES + 255) / 256;
    const int oblk = (out_size + 255) / 256;
    const int mt   = (NODES + 127) / 128;
    const int cvt_total = NODES * 44 + 512 * 352 + 512 * 512 + 128 * 512;

    auto L = [&](int phase, int aux, dim3 grid, size_t shmem,
                 const u16* gA = nullptr, const u16* gB = nullptr,
                 u16* gC = nullptr, const float* gBias = nullptr,
                 const float* gAs = nullptr, const float* gAd = nullptr,
                 int gM = 0, int gN = 0, int gK = 0, int gAct = 0) {
        BaselineGAT_41764261987077_kernel<<<grid, 256, shmem, stream>>>(
            phase, aux, x, ei, W1, as1, ad1, b1, W2, as2, ad2, b2,
            Wc1, bc1, Wc2, bc2, (float*)d_out,
            hAb, hbB, asr, ads, xb, w1t, w2t, wc1t,
            flag, cnt, tmp, bsum, boff, rowptr, cursor, col,
            gA, gB, gC, gBias, gAs, gAd, gM, gN, gK, gAct,
            NODES, E, nblk);
    };
    const size_t GSH = 49152;   // GEMM dynamic arena: 3x(8KB A + 8KB B)

    if (n_in < 14 || off > ws_size) { L(100, 1, oblk, 0); return; }

    // CSR build (detect+zero merged; scan2 folded into phase 5 lookback)
    L(0, 0, nblk + 1, 0);
    L(2, 0, eblk, 0);
    L(3, 0, nblk, 0);
    L(5, 0, nblk, 0);
    L(6, 0, eblk, 0);

    // bf16 conversions (vectorized x path)
    L(20, 0, (cvt_total + 255) / 256, 0);

    // layer 1: h1 = xb @ w1t^T (bf16) + fused alpha, agg(elu) -> hbB
    L(30, 0, dim3(mt, 4), GSH, xb, w1t, hAb, nullptr, as1, ad1, NODES, 512, 352, 0);
    L(31, 1, 4096, 0, nullptr, nullptr, nullptr, b1);      // persistent-wave agg

    // layer 2
    L(30, 0, dim3(mt, 4), GSH, hbB, w2t, hAb, nullptr, as2, ad2, NODES, 512, 512, 0);
    L(31, 0, 4096, 0, nullptr, nullptr, nullptr, b2);

    // classifier fused: relu(hbB @ wc1t^T + bc1) . Wc2 + bc2 -> out (fp32)
    L(30, 0, dim3(mt, 1), GSH, hbB, wc1t, nullptr, bc1, nullptr, nullptr, NODES, 128, 512, 2);
}

// Round 7
// 556.705 us; speedup vs baseline: 1.0726x; 1.0233x over previous
//
#include <hip/hip_runtime.h>
#include <math.h>

typedef unsigned short u16;
typedef unsigned int u32;
typedef short short8 __attribute__((ext_vector_type(8)));
typedef __bf16 bf16x8 __attribute__((ext_vector_type(8)));
typedef float f32x4 __attribute__((ext_vector_type(4)));
typedef u32 u32x4 __attribute__((ext_vector_type(4)));

typedef const __attribute__((address_space(1))) void* as1cv;
typedef __attribute__((address_space(3))) void* as3v;

__device__ __forceinline__ void gload16(const void* g, void* l) {
    // async global->LDS DMA, 16B/lane; LDS dest = uniform base + lane*16
    __builtin_amdgcn_global_load_lds((as1cv)g, (as3v)l, 16, 0, 0);
}

__device__ __forceinline__ float b2f(u16 u) {
    union { u32 i; float f; } v; v.i = ((u32)u) << 16; return v.f;
}
__device__ __forceinline__ float b2f_lo(u32 q) {
    union { u32 i; float f; } v; v.i = q << 16; return v.f;
}
__device__ __forceinline__ float b2f_hi(u32 q) {
    union { u32 i; float f; } v; v.i = q & 0xffff0000u; return v.f;
}
__device__ __forceinline__ u16 f2b(float f) {
    union { float f; u32 i; } v; v.f = f;
    u32 i = v.i;
    u32 r = (i + 0x7fffu + ((i >> 16) & 1u)) >> 16;   // RNE fp32 -> bf16
    return (u16)r;
}
__device__ __forceinline__ u32 pack2(u16 a, u16 b) { return (u32)a | ((u32)b << 16); }

// ---------- device helpers (all phases live in the ONE named kernel) ----------

// segment softmax + aggregate. Persistent waves (grid 4096 blocks = 16K waves);
// lane l owns channels 8l..8l+7 (head = l>>4). No max-subtraction (|e| small).
// v3: exact tail — full 8-groups, one 4-group, <=3 singles; SGPR gather bases
// via readfirstlane (wave-uniform indices, scalar col loads).
__device__ void agg_dev(const int* __restrict__ rowptr, const int* __restrict__ col,
                        const float* __restrict__ asrc, const float* __restrict__ adst,
                        const u16* __restrict__ hb, const float* __restrict__ bias,
                        u16* __restrict__ outb, int elu, int NODES) {
    const int wid = __builtin_amdgcn_readfirstlane((blockIdx.x * 256 + threadIdx.x) >> 6);
    const int nwaves = gridDim.x << 2;
    const int l = threadIdx.x & 63;
    const int hd = l >> 4;
    const int cbase = 8 * l;
    float bv[8];
#pragma unroll
    for (int c = 0; c < 8; c++) bv[c] = bias[cbase + c];

    for (int n = wid; n < NODES; n += nwaves) {
        const int beg = __builtin_amdgcn_readfirstlane(rowptr[n]);
        const int end = __builtin_amdgcn_readfirstlane(rowptr[n + 1]);
        const float ad = adst[n * 4 + hd];
        float acc0[8], acc1[8];
#pragma unroll
        for (int c = 0; c < 8; c++) { acc0[c] = 0.f; acc1[c] = 0.f; }
        float ss0 = 0.f, ss1 = 0.f;
        int j = beg;
        for (; j + 8 <= end; j += 8) {             // full 8-groups (8 gathers in flight)
            int s[8];
#pragma unroll
            for (int q = 0; q < 8; q++) s[q] = __builtin_amdgcn_readfirstlane(col[j + q]);
            u32x4 g[8];
#pragma unroll
            for (int q = 0; q < 8; q++)
                g[q] = *(const u32x4*)(hb + (size_t)s[q] * 512 + cbase);
            float p[8];
#pragma unroll
            for (int q = 0; q < 8; q++) {
                float e = asrc[(size_t)s[q] * 4 + hd] + ad;
                e = e > 0.f ? e : 0.2f * e;
                p[q] = __expf(e);
            }
#pragma unroll
            for (int q = 0; q < 8; q += 2) {
                ss0 += p[q]; ss1 += p[q + 1];
#pragma unroll
                for (int u = 0; u < 4; u++) {
                    acc0[2 * u]     += p[q]     * b2f_lo(g[q][u]);
                    acc0[2 * u + 1] += p[q]     * b2f_hi(g[q][u]);
                    acc1[2 * u]     += p[q + 1] * b2f_lo(g[q + 1][u]);
                    acc1[2 * u + 1] += p[q + 1] * b2f_hi(g[q + 1][u]);
                }
            }
        }
        if (j + 4 <= end) {                        // one 4-group
            int s[4];
#pragma unroll
            for (int q = 0; q < 4; q++) s[q] = __builtin_amdgcn_readfirstlane(col[j + q]);
            u32x4 g[4];
#pragma unroll
            for (int q = 0; q < 4; q++)
                g[q] = *(const u32x4*)(hb + (size_t)s[q] * 512 + cbase);
            float p[4];
#pragma unroll
            for (int q = 0; q < 4; q++) {
                float e = asrc[(size_t)s[q] * 4 + hd] + ad;
                e = e > 0.f ? e : 0.2f * e;
                p[q] = __expf(e);
            }
#pragma unroll
            for (int q = 0; q < 4; q += 2) {
                ss0 += p[q]; ss1 += p[q + 1];
#pragma unroll
                for (int u = 0; u < 4; u++) {
                    acc0[2 * u]     += p[q]     * b2f_lo(g[q][u]);
                    acc0[2 * u + 1] += p[q]     * b2f_hi(g[q][u]);
                    acc1[2 * u]     += p[q + 1] * b2f_lo(g[q + 1][u]);
                    acc1[2 * u + 1] += p[q + 1] * b2f_hi(g[q + 1][u]);
                }
            }
            j += 4;
        }
        for (; j < end; ++j) {                     // <=3 singles
            int s0 = __builtin_amdgcn_readfirstlane(col[j]);
            u32x4 g0 = *(const u32x4*)(hb + (size_t)s0 * 512 + cbase);
            float e = asrc[(size_t)s0 * 4 + hd] + ad;
            e = e > 0.f ? e : 0.2f * e;
            float p0 = __expf(e);
            ss0 += p0;
#pragma unroll
            for (int u = 0; u < 4; u++) {
                acc0[2 * u]     += p0 * b2f_lo(g0[u]);
                acc0[2 * u + 1] += p0 * b2f_hi(g0[u]);
            }
        }
        float inv = 1.f / (ss0 + ss1 + 1e-16f);
        float v[8];
#pragma unroll
        for (int c = 0; c < 8; c++) {
            float tv = (acc0[c] + acc1[c]) * inv + bv[c];
            if (elu) tv = tv > 0.f ? tv : expm1f(tv);
            v[c] = tv;
        }
        u32x4 ov;
        ov[0] = pack2(f2b(v[0]), f2b(v[1]));
        ov[1] = pack2(f2b(v[2]), f2b(v[3]));
        ov[2] = pack2(f2b(v[4]), f2b(v[5]));
        ov[3] = pack2(f2b(v[6]), f2b(v[7]));
        *(u32x4*)(outb + (size_t)n * 512 + cbase) = ov;
    }
}

// MFMA GEMM: acc = A bf16[M,K] @ Bt bf16[N,K]^T, fp32 accum.
// 128x128 tile, 4 waves 2x2, K multiple of 32 (>=96).
// v7: 1D grid (nwg passed explicitly; gy = N/128 decoded from args) so the
//     launch can append unrelated work blocks (scatter) after the GEMM blocks.
//     K-loop: 3-buffer lead-3 counted-vmcnt pipeline (v5). Source-swizzled
//     gload_lds staging (conflict-free ds_read_b128); bijective XCD-chunk remap.
// act 0: store C bf16.  act 1: relu(+bias), store C bf16.
// act 2: relu(+bias), NO C store; fused logits: out[row,k] = z-row . Wc2 + bc2.
// aS != nullptr (with act 0): fused alpha epilogue (stores C too).
__device__ void gemm_dev(const u16* __restrict__ A, const u16* __restrict__ Bt,
                         u16* __restrict__ C, const float* __restrict__ bias,
                         const float* __restrict__ aS, const float* __restrict__ aD,
                         float* __restrict__ asr, float* __restrict__ ads,
                         const float* __restrict__ Wc2, const float* __restrict__ bc2,
                         float* __restrict__ outp,
                         int M, int N, int K, int act, char* shm, int nwg) {
    const int t = threadIdx.x;
    const int l = t & 63, w = t >> 6;

    u16* As0 = (u16*)shm;
    u16* As1 = (u16*)(shm + 8192);
    u16* As2 = (u16*)(shm + 16384);
    u16* Bs0 = (u16*)(shm + 24576);
    u16* Bs1 = (u16*)(shm + 32768);
    u16* Bs2 = (u16*)(shm + 40960);

    // ---- XCD-aware bijective remap (m204): hw flat id -> contiguous logical chunk per XCD
    const int fid = blockIdx.x;
    int logical;
    {
        const int q = nwg >> 3, r = nwg & 7;
        const int xcd = fid & 7, ix = fid >> 3;
        logical = (xcd < r ? xcd * (q + 1) : r * (q + 1) + (xcd - r) * q) + ix;
    }
    const int gy = N >> 7;                   // head-blocks per m-tile
    const int mtile = logical / gy;          // adjacent logicals share mtile (A panel reuse)
    const int hd_ = logical - mtile * gy;
    const int m0 = mtile * 128, n0 = hd_ * 128;

    const int wm = (w >> 1) * 64, wn = (w & 1) * 64;

    // ---- staging: wave w owns rows [32w, 32w+32) of both tiles, 2 chunks of 16 rows.
    // LDS linear [128][32] u16; content slot-swizzled: LDS(row, sa) = G(row, sa ^ ((row>>1)&3)).
    const int rl0 = w * 32 + (l >> 2);
    const int rl1 = rl0 + 16;
    const int gso = 8 * ((l & 3) ^ ((l >> 3) & 3));    // swizzled 16B slot in source row
    const u16* pA0 = A + (size_t)min(m0 + rl0, M - 1) * K + gso;
    const u16* pA1 = A + (size_t)min(m0 + rl1, M - 1) * K + gso;
    const u16* pB0 = Bt + (size_t)min(n0 + rl0, N - 1) * K + gso;
    const u16* pB1 = Bt + (size_t)min(n0 + rl1, N - 1) * K + gso;
    const int wbase = (w * 32) * 32;                   // wave-uniform LDS elem offset

    // ---- fragment-read offsets (apply the same swizzle)
    const int rs = ((l & 15) >> 1) & 3;
    const int roff = 8 * ((l >> 4) ^ rs);              // u16 elems within the 32-elem row

    f32x4 acc[4][4];
    f32x4 z4 = {0.f, 0.f, 0.f, 0.f};
#pragma unroll
    for (int i = 0; i < 4; i++)
#pragma unroll
        for (int j = 0; j < 4; j++) acc[i][j] = z4;

    auto STAGE = [&](u16* As_, u16* Bs_, int k0) {
        gload16(pA0 + k0, As_ + wbase);
        gload16(pA1 + k0, As_ + wbase + 16 * 32);
        gload16(pB0 + k0, Bs_ + wbase);
        gload16(pB1 + k0, Bs_ + wbase + 16 * 32);
    };
    auto COMP = [&](const u16* As_, const u16* Bs_) {
        bf16x8 af[4], bfr[4];
#pragma unroll
        for (int i = 0; i < 4; i++) {
            af[i]  = *(const bf16x8*)(As_ + (wm + i * 16 + (l & 15)) * 32 + roff);
            bfr[i] = *(const bf16x8*)(Bs_ + (wn + i * 16 + (l & 15)) * 32 + roff);
        }
        __builtin_amdgcn_s_setprio(1);
#pragma unroll
        for (int i = 0; i < 4; i++)
#pragma unroll
            for (int j = 0; j < 4; j++)
                acc[i][j] = __builtin_amdgcn_mfma_f32_16x16x32_bf16(af[i], bfr[j], acc[i][j], 0, 0, 0);
        __builtin_amdgcn_s_setprio(0);
    };
    auto WSEL = [&](int s_, int ns_) {
        int ahead = ns_ - 1 - s_;                      // tiles staged beyond s (<=2)
        if (ahead >= 2)      asm volatile("s_waitcnt vmcnt(8)" ::: "memory");
        else if (ahead == 1) asm volatile("s_waitcnt vmcnt(4)" ::: "memory");
        else                 asm volatile("s_waitcnt vmcnt(0)" ::: "memory");
    };

    const int ns = K >> 5;                 // K-steps of 32 (ns >= 3 for all our shapes)
    STAGE(As0, Bs0, 0);
    STAGE(As1, Bs1, 32);
    STAGE(As2, Bs2, 64);
    int s = 0;
    while (true) {
        WSEL(s, ns); __builtin_amdgcn_s_barrier();
        COMP(As0, Bs0); __builtin_amdgcn_s_barrier();
        if (s + 3 < ns) STAGE(As0, Bs0, (s + 3) << 5);
        if (++s >= ns) break;
        WSEL(s, ns); __builtin_amdgcn_s_barrier();
        COMP(As1, Bs1); __builtin_amdgcn_s_barrier();
        if (s + 3 < ns) STAGE(As1, Bs1, (s + 3) << 5);
        if (++s >= ns) break;
        WSEL(s, ns); __builtin_amdgcn_s_barrier();
        COMP(As2, Bs2); __builtin_amdgcn_s_barrier();
        if (s + 3 < ns) STAGE(As2, Bs2, (s + 3) << 5);
        if (++s >= ns) break;
    }
    // all waves passed the final barrier; LDS arena is free for epilogues.

    if (act == 2) {
        // fused classifier epilogue: z = relu(acc + bias); logits = z . Wc2 + bc2
        float* wl = (float*)shm;               // 1280 floats Wc2 + 10 bc2
        float (*logbuf)[128][10] = (float (*)[128][10])(shm + 8192);  // 10240 B
        for (int i = t; i < 1280; i += 256) wl[i] = Wc2[i];
        if (t < 10) wl[1280 + t] = bc2[t];
        __syncthreads();
        int cj[4];
#pragma unroll
        for (int j = 0; j < 4; j++) cj[j] = wn + j * 16 + (l & 15);
#pragma unroll
        for (int i = 0; i < 4; i++) {
#pragma unroll
            for (int r = 0; r < 4; r++) {
                float zv[4];
#pragma unroll
                for (int j = 0; j < 4; j++) {
                    float v = acc[i][j][r] + (bias ? bias[cj[j]] : 0.f);
                    zv[j] = v > 0.f ? v : 0.f;
                }
                float part[10];
#pragma unroll
                for (int k = 0; k < 10; k++) {
                    float s2 = 0.f;
#pragma unroll
                    for (int j = 0; j < 4; j++) s2 += zv[j] * wl[cj[j] * 10 + k];
#pragma unroll
                    for (int o = 1; o < 16; o <<= 1) s2 += __shfl_xor(s2, o);
                    part[k] = s2;
                }
                if ((l & 15) == 0) {
                    int rl = wm + i * 16 + (l >> 4) * 4 + r;
#pragma unroll
                    for (int k = 0; k < 10; k++) logbuf[w & 1][rl][k] = part[k];
                }
            }
        }
        __syncthreads();
        if (t < 128) {
            int row = m0 + t;
            if (row < M) {
#pragma unroll
                for (int k = 0; k < 10; k++)
                    outp[(size_t)row * 10 + k] =
                        logbuf[0][t][k] + logbuf[1][t][k] + wl[1280 + k];
            }
        }
        return;
    }

#pragma unroll
    for (int i = 0; i < 4; i++) {
        int rbase = m0 + wm + i * 16 + (l >> 4) * 4;
#pragma unroll
        for (int j = 0; j < 4; j++) {
            int c = n0 + wn + j * 16 + (l & 15);
            float bv = bias ? bias[c] : 0.f;
#pragma unroll
            for (int r = 0; r < 4; r++) {
                int row = rbase + r;
                if (row < M) {
                    float v = acc[i][j][r] + bv;
                    if (act == 1) v = v > 0.f ? v : 0.f;
                    C[(size_t)row * N + c] = f2b(v);
                }
            }
        }
    }

    if (aS) {   // fused alpha epilogue; head hd = n0/128
        float (*red)[128][2] = (float (*)[128][2])shm;   // alias arena (free after loop)
        const int hd = n0 >> 7;
        float aSv[4], aDv[4];
#pragma unroll
        for (int j = 0; j < 4; j++) {
            int c = n0 + wn + j * 16 + (l & 15);
            aSv[j] = aS[c];
            aDv[j] = aD[c];
        }
#pragma unroll
        for (int i = 0; i < 4; i++) {
#pragma unroll
            for (int r = 0; r < 4; r++) {
                float vs = 0.f, vd = 0.f;
#pragma unroll
                for (int j = 0; j < 4; j++) {
                    float hv = acc[i][j][r];
                    vs += hv * aSv[j];
                    vd += hv * aDv[j];
                }
#pragma unroll
                for (int o = 1; o < 16; o <<= 1) {
                    vs += __shfl_xor(vs, o);
                    vd += __shfl_xor(vd, o);
                }
                if ((l & 15) == 0) {
                    int rl = wm + i * 16 + (l >> 4) * 4 + r;
                    red[w & 1][rl][0] = vs;
                    red[w & 1][rl][1] = vd;
                }
            }
        }
        __syncthreads();
        if (t < 128) {
            int row = m0 + t;
            if (row < M) {
                asr[row * 4 + hd] = red[0][t][0] + red[1][t][0];
                ads[row * 4 + hd] = red[0][t][1] + red[1][t][1];
            }
        }
    }
}

__global__ __launch_bounds__(256) void BaselineGAT_41764261987077_kernel(
    int phase, int aux,
    const float* x, const int* ei,
    const float* W1, const float* as1, const float* ad1, const float* b1,
    const float* W2, const float* as2, const float* ad2, const float* b2,
    const float* Wc1, const float* bc1, const float* Wc2, const float* bc2,
    float* out,
    u16* hAb, u16* hbB, float* asr, float* ads,
    u16* xb, u16* w1t, u16* w2t, u16* wc1t,
    int* flag, int* cnt, int* tmp, int* bsum, int* boff,
    int* rowptr, int* cursor, int* col,
    const u16* gA, const u16* gB, u16* gC, const float* gBias,
    const float* gAs, const float* gAd,
    int gM, int gN, int gK, int gAct,
    int NODES, int E, int nblk)
{
    // 4KB static (scan/flag buffers) + dynamic GEMM arena (48KB on phase-30 launches only)
    __shared__ int sstat[1024];
    extern __shared__ char dynshm[];
    int* smi = sstat;                 // phases 0,3 (uses [0..256])
    int* smb = sstat + 512;           // phase 5 lookback scan

    const int t = threadIdx.x;
    const int gid = blockIdx.x * 256 + t;
    const int EN = E + NODES;

    switch (phase) {
    case 100: {   // ws-sentinel paint only
        if (gid < NODES * 10) out[gid] = 1000.0f;
    } break;
    case 0: {     // 1 block: edge dtype detect (cnt zeroed via hipMemsetAsync)
        if (t == 0) smi[256] = 0;
        __syncthreads();
        for (int j = t; j < 1024; j += 256)
            if (ei[2 * j + 1] != 0) atomicAdd(&smi[256], 1);
        __syncthreads();
        if (t == 0) flag[0] = (smi[256] < 16) ? 2 : 1;
    } break;
    case 2: {     // MERGED: histogram (blocks < aux=eblk) + bf16 conversions (rest)
        if ((int)blockIdx.x < aux) {
            if (gid >= EN) return;
            int step = flag[0];
            int d;
            if (gid < E) {
                d = ei[(size_t)(E + gid) * step];
                if ((unsigned)d >= (unsigned)NODES) d = 0;
            } else d = gid - E;
            atomicAdd(&cnt[d], 1);
            return;
        }
        int i = (blockIdx.x - aux) * 256 + t;
        const int XC = NODES * 44;            // 8-elem chunks of xb rows (352/8)
        if (i < XC) {
            int n = i / 44, kk = (i - n * 44) * 8;
            short8 o;
            if (kk < 336) {
                const f32x4* xp = (const f32x4*)(x + (size_t)n * 336 + kk);
                f32x4 f0 = xp[0], f1 = xp[1];
                o[0] = (short)f2b(f0[0]); o[1] = (short)f2b(f0[1]);
                o[2] = (short)f2b(f0[2]); o[3] = (short)f2b(f0[3]);
                o[4] = (short)f2b(f1[0]); o[5] = (short)f2b(f1[1]);
                o[6] = (short)f2b(f1[2]); o[7] = (short)f2b(f1[3]);
            } else {
#pragma unroll
                for (int e = 0; e < 8; e++) o[e] = 0;
            }
            *(short8*)(xb + (size_t)n * 352 + kk) = o;
            return;
        }
        i -= XC;
        if (i < 512 * 352) {          // W1 [336,512] -> w1t [512,352] T+pad
            int n = i / 352, k = i - n * 352;
            w1t[i] = (k < 336) ? f2b(W1[(size_t)k * 512 + n]) : (u16)0;
            return;
        }
        i -= 512 * 352;
        if (i < 512 * 512) {          // W2 [512,512] -> w2t [512,512] T
            int n = i >> 9, k = i & 511;
            w2t[i] = f2b(W2[(size_t)k * 512 + n]);
            return;
        }
        i -= 512 * 512;
        if (i < 128 * 512) {          // Wc1 [512,128] -> wc1t [128,512] T
            int n = i >> 9, k = i & 511;
            wc1t[i] = f2b(Wc1[(size_t)k * 128 + n]);
        }
    } break;
    case 3: {     // block-local inclusive scan
        smi[t] = (gid < NODES) ? cnt[gid] : 0;
        __syncthreads();
        for (int o = 1; o < 256; o <<= 1) {
            int add = (t >= o) ? smi[t - o] : 0;
            __syncthreads();
            smi[t] += add;
            __syncthreads();
        }
        if (gid < NODES) tmp[gid] = smi[t];
        if (t == 255) bsum[blockIdx.x] = smi[255];
    } break;
    case 5: {     // rowptr + cursor, with inline lookback scan of bsum
        smb[t] = (t < nblk) ? bsum[t] : 0;
        __syncthreads();
        for (int o = 1; o < 256; o <<= 1) {
            int add = (t >= o) ? smb[t - o] : 0;
            __syncthreads();
            smb[t] += add;
            __syncthreads();
        }
        int base = (blockIdx.x == 0) ? 0 : smb[blockIdx.x - 1];
        if (gid >= NODES) return;
        int incl = tmp[gid] + base;
        rowptr[gid + 1] = incl;
        cursor[gid] = incl - cnt[gid];
        if (gid == 0) rowptr[0] = 0;
    } break;
    case 30: {    // MERGED: GEMM (blocks < aux=nwgemm) + CSR scatter (rest, L1 only)
        if ((int)blockIdx.x < aux) {
            gemm_dev(gA, gB, gC, gBias, gAs, gAd, asr, ads,
                     Wc2, bc2, out, gM, gN, gK, gAct, dynshm, aux);
            return;
        }
        int g2 = (blockIdx.x - aux) * 256 + t;
        if (g2 >= EN) return;
        int step = flag[0];
        int d, s;
        if (g2 < E) {
            s = ei[(size_t)g2 * step];
            d = ei[(size_t)(E + g2) * step];
            if ((unsigned)s >= (unsigned)NODES) s = 0;
            if ((unsigned)d >= (unsigned)NODES) d = 0;
        } else { d = g2 - E; s = d; }
        int pos = atomicAdd(&cursor[d], 1);
        col[pos] = s;
    } break;
    case 31: agg_dev(rowptr, col, asr, ads, hAb, gBias, hbB, aux, NODES); break;
    }
}

extern "C" void kernel_launch(void* const* d_in, const int* in_sizes, int n_in,
                              void* d_out, int out_size, void* d_ws, size_t ws_size,
                              hipStream_t stream) {
    const float* x   = (const float*)d_in[0];
    const int*   ei  = (const int*)d_in[1];
    const float* W1  = (const float*)d_in[2];
    const float* as1 = (const float*)d_in[3];
    const float* ad1 = (const float*)d_in[4];
    const float* b1  = (const float*)d_in[5];
    const float* W2  = (const float*)d_in[6];
    const float* as2 = (const float*)d_in[7];
    const float* ad2 = (const float*)d_in[8];
    const float* b2  = (const float*)d_in[9];
    const float* Wc1 = (const float*)d_in[10];
    const float* bc1 = (const float*)d_in[11];
    const float* Wc2 = (const float*)d_in[12];
    const float* bc2 = (const float*)d_in[13];

    const int NODES = in_sizes[0] / 336;   // 50000
    const int E     = in_sizes[1] / 2;     // 500000

    char* ws = (char*)d_ws;
    size_t off = 0;
    auto alloc = [&](size_t b) -> char* {
        char* p = ws + off; off = (off + b + 255) & ~(size_t)255; return p;
    };
    u16*   xb   = (u16*)alloc((size_t)NODES * 352 * 2);
    u16*   hAb  = (u16*)alloc((size_t)NODES * 512 * 2);   // GEMM out (bf16)
    u16*   hbB  = (u16*)alloc((size_t)NODES * 512 * 2);   // agg out (bf16)
    float* asr  = (float*)alloc((size_t)NODES * 4 * 4);
    float* ads  = (float*)alloc((size_t)NODES * 4 * 4);
    u16*   w1t  = (u16*)alloc((size_t)512 * 352 * 2);
    u16*   w2t  = (u16*)alloc((size_t)512 * 512 * 2);
    u16*   wc1t = (u16*)alloc((size_t)128 * 512 * 2);
    int* flag   = (int*)alloc(256);
    int* cnt    = (int*)alloc((size_t)NODES * 4);
    int* tmp    = (int*)alloc((size_t)NODES * 4);
    int* bsum   = (int*)alloc(4096);
    int* boff   = (int*)alloc(4096);
    int* rowptr = (int*)alloc((size_t)(NODES + 1) * 4);
    int* cursor = (int*)alloc((size_t)NODES * 4);
    int* col    = (int*)alloc((size_t)(E + NODES) * 4);

    const int nblk = (NODES + 255) / 256;
    const int eblk = (E + NODES + 255) / 256;
    const int oblk = (out_size + 255) / 256;
    const int mt   = (NODES + 127) / 128;      // 391 m-tiles
    const int cvt_total = NODES * 44 + 512 * 352 + 512 * 512 + 128 * 512;
    const int cvtblk = (cvt_total + 255) / 256;

    auto L = [&](int phase, int aux, dim3 grid, size_t shmem,
                 const u16* gA = nullptr, const u16* gB = nullptr,
                 u16* gC = nullptr, const float* gBias = nullptr,
                 const float* gAs = nullptr, const float* gAd = nullptr,
                 int gM = 0, int gN = 0, int gK = 0, int gAct = 0) {
        BaselineGAT_41764261987077_kernel<<<grid, 256, shmem, stream>>>(
            phase, aux, x, ei, W1, as1, ad1, b1, W2, as2, ad2, b2,
            Wc1, bc1, Wc2, bc2, (float*)d_out,
            hAb, hbB, asr, ads, xb, w1t, w2t, wc1t,
            flag, cnt, tmp, bsum, boff, rowptr, cursor, col,
            gA, gB, gC, gBias, gAs, gAd, gM, gN, gK, gAct,
            NODES, E, nblk);
    };
    const size_t GSH = 49152;   // GEMM dynamic arena: 3x(8KB A + 8KB B)

    if (n_in < 14 || off > ws_size) { L(100, 1, oblk, 0); return; }

    // CSR build + conversions, compacted launch chain:
    hipMemsetAsync(cnt, 0, (size_t)NODES * 4, stream);   // zero histogram
    L(0, 0, 1, 0);                                       // dtype detect only
    L(2, eblk, eblk + cvtblk, 0);                        // histogram ∥ bf16 conversions
    L(3, 0, nblk, 0);                                    // block scan
    L(5, 0, nblk, 0);                                    // rowptr + cursor (lookback)

    // layer 1 GEMM ∥ CSR scatter (scatter blocks backfill as GEMM drains)
    L(30, mt * 4, mt * 4 + eblk, GSH, xb, w1t, hAb, nullptr, as1, ad1, NODES, 512, 352, 0);
    L(31, 1, 4096, 0, nullptr, nullptr, nullptr, b1);    // agg(elu) -> hbB

    // layer 2
    L(30, mt * 4, mt * 4, GSH, hbB, w2t, hAb, nullptr, as2, ad2, NODES, 512, 512, 0);
    L(31, 0, 4096, 0, nullptr, nullptr, nullptr, b2);

    // classifier fused: relu(hbB @ wc1t^T + bc1) . Wc2 + bc2 -> out (fp32)
    L(30, mt, mt, GSH, hbB, wc1t, nullptr, bc1, nullptr, nullptr, NODES, 128, 512, 2);
}